// Round 1
// 490.582 us; speedup vs baseline: 1.0101x; 1.0101x over previous
//
#include <hip/hip_runtime.h>
#include <hip/hip_fp16.h>
#include <math.h>

constexpr int D = 64;
constexpr int BROWS = 128;          // dst rows per bucket (bucket = dst >> 7)
constexpr int BCAP  = 6016;         // record capacity per bucket
constexpr int PASS1_CHUNK = 4096;   // edges per workgroup in pass 1
constexpr int NBMAX = 2048;
constexpr int WROW = 136;           // fp16 LDS row stride (128 + 8 pad)

typedef _Float16 half8 __attribute__((ext_vector_type(8)));
typedef float    f32x4 __attribute__((ext_vector_type(4)));

__device__ __forceinline__ float wave_reduce_sum(float v) {
    #pragma unroll
    for (int m = 1; m < 64; m <<= 1)
        v += __shfl_xor(v, m, 64);
    return v;
}

__device__ __forceinline__ void h8_to_f8(uint4 h, float* f) {
    const __half2* hp = reinterpret_cast<const __half2*>(&h);
    #pragma unroll
    for (int i = 0; i < 4; ++i) {
        float2 t = __half22float2(hp[i]);
        f[2 * i] = t.x; f[2 * i + 1] = t.y;
    }
}

__device__ __forceinline__ uint4 f8_to_h8(const float* f) {
    uint4 r;
    unsigned* rp = &r.x;
    #pragma unroll
    for (int i = 0; i < 4; ++i) {
        __half2 h = __floats2half2_rn(f[2 * i], f[2 * i + 1]);
        rp[i] = *reinterpret_cast<unsigned*>(&h);
    }
    return r;
}

// ---- L0: user embeddings = l2norm(user_w) -> x0 fp16, wave per row ----
__global__ void k_user_norm(const float* __restrict__ user_w,
                            __half* __restrict__ x, int U_) {
    int wid  = (blockIdx.x * blockDim.x + threadIdx.x) >> 6;
    int lane = threadIdx.x & 63;
    if (wid >= U_) return;
    size_t o = (size_t)wid * D + lane;
    float v  = user_w[o];
    float ss = wave_reduce_sum(v * v);
    x[o] = __float2half(v / fmaxf(sqrtf(ss), 1e-12f));
}

// ---- L0 item projection as MFMA GEMM: [64 items/block] x [128 k] x [64 d].
__global__ void __launch_bounds__(256) k_item(
        const float* __restrict__ audio,
        const float* __restrict__ artist_w, const float* __restrict__ album_w,
        const float* __restrict__ proj_W,   const float* __restrict__ proj_b,
        const int* __restrict__ artist_ids, const int* __restrict__ album_ids,
        __half* __restrict__ x, int I_, int U_) {
    __shared__ __align__(16) __half Wh[64 * WROW];      // proj_W in fp16
    __shared__ __align__(16) __half feat[4 * 16 * WROW]; // per-wave 16x128

    const int tid  = threadIdx.x;
    const int lane = tid & 63;
    const int wv   = tid >> 6;
    const int n    = lane & 15;       // d within tile / m within tile
    const int quad = lane >> 4;

    for (int idx = tid; idx < 64 * 128; idx += 256) {
        int d = idx >> 7, k = idx & 127;
        Wh[d * WROW + k] = __float2half(proj_W[idx]);
    }
    __syncthreads();

    half8 bfrag[4][4];
    #pragma unroll
    for (int dg = 0; dg < 4; ++dg)
        #pragma unroll
        for (int c = 0; c < 4; ++c)
            bfrag[dg][c] = *reinterpret_cast<const half8*>(
                &Wh[(dg * 16 + n) * WROW + c * 32 + quad * 8]);

    __half* fw = &feat[wv * 16 * WROW];
    const int itemBase = blockIdx.x * 64 + wv * 16;
    #pragma unroll 4
    for (int it = 0; it < 16; ++it) {
        int item = itemBase + it;
        float a = 0.f, m = 0.f;
        if (item < I_) {
            a = audio[(size_t)item * D + lane];
            int aid = artist_ids[item], bid = album_ids[item];
            m = artist_w[(size_t)aid * D + lane] +
                album_w[(size_t)bid * D + lane];
        }
        fw[it * WROW + lane]      = __float2half(a);
        fw[it * WROW + 64 + lane] = __float2half(m);
    }
    __syncthreads();

    half8 afrag[4];
    #pragma unroll
    for (int c = 0; c < 4; ++c)
        afrag[c] = *reinterpret_cast<const half8*>(
            &fw[n * WROW + c * 32 + quad * 8]);

    f32x4 acc[4];
    #pragma unroll
    for (int dg = 0; dg < 4; ++dg) {
        f32x4 t = {0.f, 0.f, 0.f, 0.f};
        #pragma unroll
        for (int c = 0; c < 4; ++c)
            t = __builtin_amdgcn_mfma_f32_16x16x32_f16(afrag[c], bfrag[dg][c],
                                                       t, 0, 0, 0);
        acc[dg] = t;
    }

    float bias[4];
    #pragma unroll
    for (int dg = 0; dg < 4; ++dg) bias[dg] = proj_b[dg * 16 + n];

    float val[4][4], ss[4];
    #pragma unroll
    for (int r = 0; r < 4; ++r) {
        float s = 0.f;
        #pragma unroll
        for (int dg = 0; dg < 4; ++dg) {
            float v = acc[dg][r] + bias[dg];
            val[dg][r] = v;
            s = fmaf(v, v, s);
        }
        s += __shfl_xor(s, 1, 64);
        s += __shfl_xor(s, 2, 64);
        s += __shfl_xor(s, 4, 64);
        s += __shfl_xor(s, 8, 64);
        ss[r] = s;
    }

    #pragma unroll
    for (int r = 0; r < 4; ++r) {
        int item = itemBase + quad * 4 + r;
        if (item >= I_) continue;
        float inv = 1.0f / fmaxf(sqrtf(ss[r]), 1e-12f);
        size_t rowo = (size_t)(U_ + item) * D + n;
        #pragma unroll
        for (int dg = 0; dg < 4; ++dg)
            x[rowo + dg * 16] = __float2half(val[dg][r] * inv);
    }
}

// ---- pass 1: scatter FAT records (dst_local|src, weight) into buckets ----
__global__ void __launch_bounds__(256) k_scatter1(
        const int* __restrict__ u_idx, const int* __restrict__ i_idx,
        const float* __restrict__ ew,
        uint2* __restrict__ records, int* __restrict__ gCursor,
        int E_, int U_, int NB) {
    __shared__ int hist[NBMAX];
    __shared__ int base[NBMAX];
    const int tid = threadIdx.x;
    const int e0 = blockIdx.x * PASS1_CHUNK;
    int uu[16], vv[16]; unsigned wb[16];
    for (int b = tid; b < NB; b += 256) hist[b] = 0;
    __syncthreads();
    #pragma unroll
    for (int j = 0; j < 16; ++j) {
        int e = e0 + j * 256 + tid;
        uu[j] = -1;
        if (e < E_) {
            int u = u_idx[e];
            int v = U_ + i_idx[e];
            float w = fmaxf(ew[e], 1e-6f);
            uu[j] = u; vv[j] = v; wb[j] = __float_as_uint(w);
            atomicAdd(&hist[u >> 7], 1);
            atomicAdd(&hist[v >> 7], 1);
        }
    }
    __syncthreads();
    for (int b = tid; b < NB; b += 256) {
        int c = hist[b];
        base[b] = c ? atomicAdd(&gCursor[b], c) : 0;
        hist[b] = 0;                      // reuse as local cursor
    }
    __syncthreads();
    #pragma unroll
    for (int j = 0; j < 16; ++j) {
        if (uu[j] >= 0) {
            int u = uu[j], v = vv[j];
            int bu = u >> 7, bv = v >> 7;
            int offu = base[bu] + atomicAdd(&hist[bu], 1);
            if (offu < BCAP)   // dst=u, src=v(item node)
                records[(size_t)bu * BCAP + offu] =
                    make_uint2(((unsigned)(u & 127) << 18) | (unsigned)v, wb[j]);
            int offv = base[bv] + atomicAdd(&hist[bv], 1);
            if (offv < BCAP)   // dst=v, src=u
                records[(size_t)bv * BCAP + offv] =
                    make_uint2(((unsigned)(v & 127) << 18) | (unsigned)u, wb[j]);
        }
    }
}

// ---- exclusive scan over bucket counts (single block) ----
__global__ void __launch_bounds__(1024) k_bscan(const int* __restrict__ gCursor,
                                                int* __restrict__ bucketBase,
                                                int NB) {
    __shared__ int s[1024];
    int t = threadIdx.x;
    int e0 = (2 * t     < NB) ? min(gCursor[2 * t], BCAP)     : 0;
    int e1 = (2 * t + 1 < NB) ? min(gCursor[2 * t + 1], BCAP) : 0;
    int x = e0 + e1;
    s[t] = x; __syncthreads();
    for (int off = 1; off < 1024; off <<= 1) {
        int v = (t >= off) ? s[t - off] : 0;
        __syncthreads();
        s[t] += v;
        __syncthreads();
    }
    int excl = s[t] - x;
    if (2 * t     < NB) bucketBase[2 * t]     = excl;
    if (2 * t + 1 < NB) bucketBase[2 * t + 1] = excl + e0;
}

// ---- pass 2: per bucket, LDS counting-sort of fat records -> packed 4B ents
//      (wfix14<<18 | src18) + rowptr + dinv, plus fused yA scale. ----
__global__ void __launch_bounds__(256) k_build(
        const uint2* __restrict__ records, const int* __restrict__ gCursor,
        const int* __restrict__ bucketBase,
        unsigned* __restrict__ ents, int* __restrict__ rowptr,
        float* __restrict__ dinv, uint4* __restrict__ yAv,
        int N_, int NB) {
    __shared__ int   s_cnt[BROWS];
    __shared__ int   s_cur[BROWS];
    __shared__ float s_w[BROWS];
    const int b   = blockIdx.x;
    const int tid = threadIdx.x;
    const uint2* rec = records + (size_t)b * BCAP;
    const int R     = min(gCursor[b], BCAP);
    const int gbase = bucketBase[b];
    if (tid < BROWS) { s_cnt[tid] = 0; s_w[tid] = 0.0f; }
    __syncthreads();
    // A: per-row counts
    for (int r = tid; r < R; r += 256)
        atomicAdd(&s_cnt[(rec[r].x >> 18) & 127], 1);
    __syncthreads();
    // B: exclusive scan over 128 rows -> rowptr, cursors
    int own = (tid < BROWS) ? s_cnt[tid] : 0;
    for (int off = 1; off < BROWS; off <<= 1) {
        int v = (tid >= off && tid < BROWS) ? s_cnt[tid - off] : 0;
        __syncthreads();
        if (tid < BROWS) s_cnt[tid] += v;
        __syncthreads();
    }
    if (tid < BROWS) {
        int excl = s_cnt[tid] - own;
        s_cur[tid] = excl;
        int gid = b * BROWS + tid;
        if (gid < N_) rowptr[gid] = gbase + excl;
    }
    if (b == NB - 1 && tid == 0) rowptr[N_] = gbase + R;
    __syncthreads();
    // C: place packed entries — record already holds (src, w); no gathers
    for (int r0 = 0; r0 < R; r0 += 256 * 8) {
        uint2 rc[8];
        #pragma unroll
        for (int j = 0; j < 8; ++j) {
            int r = r0 + j * 256 + tid;
            rc[j] = (r < R) ? rec[r] : make_uint2(0xFFFFFFFFu, 0);
        }
        #pragma unroll
        for (int j = 0; j < 8; ++j) {
            if (rc[j].x != 0xFFFFFFFFu) {
                int dl  = (int)((rc[j].x >> 18) & 127);
                unsigned src = rc[j].x & 0x3FFFFu;
                float w = __uint_as_float(rc[j].y);
                unsigned wfix = (unsigned)fminf(w * 16384.f + 0.5f, 16383.f);
                int pos = gbase + atomicAdd(&s_cur[dl], 1);
                ents[pos] = (wfix << 18) | src;
                atomicAdd(&s_w[dl], w);
            }
        }
    }
    __syncthreads();
    // D: dinv = rsqrt(wsum + 1)
    if (tid < BROWS) {
        int gid = b * BROWS + tid;
        if (gid < N_) {
            float di = 1.0f / sqrtf(s_w[tid] + 1.0f);
            dinv[gid] = di;
            s_w[tid] = di;
        }
    }
    __syncthreads();
    // E: scale this bucket's yA rows: y0 = dinv * x0  (16 B per lane)
    for (int t = tid; t < BROWS * 8; t += 256) {
        int r = t >> 3, c8 = t & 7;
        int gid = b * BROWS + r;
        if (gid < N_) {
            float di = s_w[r];
            size_t o = (size_t)gid * 8 + c8;
            float f[8]; h8_to_f8(yAv[o], f);
            #pragma unroll
            for (int i = 0; i < 8; ++i) f[i] *= di;
            yAv[o] = f8_to_h8(f);
        }
    }
}

// ---- propagation layer in y-domain: s = y[dst] + 2^-14 * sum wfix*y[src];
//      y_next = dinv^2 * s.  8-lane row groups, half8 (16 B) per lane.
//      Each group g strides its own CSR entries (j = beg+g, +=8): the 8
//      lanes of a group read the same 4 B ent (hw-coalesced 32 B/wave) —
//      no chunk staging, no ds_bpermute, no idx<m guards.  Edge visit
//      order per lane is identical to the chunked version (bit-exact).
// mode 0: write yn = y1; ysum = y0 + y1
// mode 1: write yn = y2; ysum += y2
// mode 2: out = l2norm(ysum + y3)        (yn unused)
__global__ void __launch_bounds__(256) k_gather(
        const uint4* __restrict__ ys, uint4* __restrict__ yn,
        uint4* __restrict__ ysum, float4* __restrict__ outp,
        const float* __restrict__ dinv, const int* __restrict__ rowptr,
        const unsigned* __restrict__ ents, int N_, int mode) {
    const int lane = threadIdx.x & 63;
    const int g  = lane >> 3;            // edge group 0..7
    const int c8 = lane & 7;             // half8 index within row
    const int wid = __builtin_amdgcn_readfirstlane(
                        (int)((blockIdx.x * blockDim.x + threadIdx.x) >> 6));
    if (wid >= N_) return;
    const int beg = rowptr[wid], end = rowptr[wid + 1];
    float a[8] = {0.f, 0.f, 0.f, 0.f, 0.f, 0.f, 0.f, 0.f};
    #pragma unroll 2
    for (int j = beg + g; j < end; j += 8) {
        unsigned e = ents[j];              // 8 lanes/group share this 4B
        float wf = (float)(e >> 18);
        int src  = (int)(e & 0x3FFFFu);
        uint4 h = ys[(size_t)src * 8 + c8];   // 128 B row / 8 lanes
        const __half2* hp = reinterpret_cast<const __half2*>(&h);
        #pragma unroll
        for (int i = 0; i < 4; ++i) {
            float2 t = __half22float2(hp[i]);
            a[2 * i]     = fmaf(wf, t.x, a[2 * i]);
            a[2 * i + 1] = fmaf(wf, t.y, a[2 * i + 1]);
        }
    }
    // reduce the 8 group partials (lanes sharing c8)
    #pragma unroll
    for (int i = 0; i < 8; ++i) {
        a[i] += __shfl_xor(a[i], 8, 64);
        a[i] += __shfl_xor(a[i], 16, 64);
        a[i] += __shfl_xor(a[i], 32, 64);
    }

    const size_t ro = (size_t)wid * 8 + c8;
    float yold[8]; h8_to_f8(ys[ro], yold);
    float di = dinv[wid], d2 = di * di;
    float fin[8];
    #pragma unroll
    for (int i = 0; i < 8; ++i)
        fin[i] = d2 * fmaf(a[i], 1.0f / 16384.0f, yold[i]);

    if (mode == 2) {
        float vs[8]; h8_to_f8(ysum[ro], vs);
        float vv[8], sq = 0.f;
        #pragma unroll
        for (int i = 0; i < 8; ++i) {
            vv[i] = vs[i] + fin[i];
            sq = fmaf(vv[i], vv[i], sq);
        }
        sq += __shfl_xor(sq, 1, 64);
        sq += __shfl_xor(sq, 2, 64);
        sq += __shfl_xor(sq, 4, 64);
        float inv = 1.0f / fmaxf(sqrtf(sq), 1e-12f);
        if (g == 0) {
            size_t ob = (size_t)wid * 16 + c8 * 2;
            outp[ob]     = make_float4(vv[0] * inv, vv[1] * inv,
                                       vv[2] * inv, vv[3] * inv);
            outp[ob + 1] = make_float4(vv[4] * inv, vv[5] * inv,
                                       vv[6] * inv, vv[7] * inv);
        }
    } else {
        if (g == 0) yn[ro] = f8_to_h8(fin);
        if (g == 1) {
            float t[8];
            if (mode == 0) {
                #pragma unroll
                for (int i = 0; i < 8; ++i) t[i] = yold[i] + fin[i];
            } else {
                float vs[8]; h8_to_f8(ysum[ro], vs);
                #pragma unroll
                for (int i = 0; i < 8; ++i) t[i] = vs[i] + fin[i];
            }
            ysum[ro] = f8_to_h8(t);
        }
    }
}

extern "C" void kernel_launch(void* const* d_in, const int* in_sizes, int n_in,
                              void* d_out, int out_size, void* d_ws, size_t ws_size,
                              hipStream_t stream) {
    const float* user_w     = (const float*)d_in[0];
    const float* audio      = (const float*)d_in[1];
    const float* artist_w   = (const float*)d_in[2];
    const float* album_w    = (const float*)d_in[3];
    const float* proj_W     = (const float*)d_in[4];
    const float* proj_b     = (const float*)d_in[5];
    const float* ew         = (const float*)d_in[6];
    const int*   u_idx      = (const int*)d_in[7];
    const int*   i_idx      = (const int*)d_in[8];
    const int*   artist_ids = (const int*)d_in[9];
    const int*   album_ids  = (const int*)d_in[10];

    const int U_ = in_sizes[0] / D;
    const int I_ = in_sizes[1] / D;
    const int E_ = in_sizes[6];
    const int N_ = U_ + I_;
    const int NB = (N_ + BROWS - 1) / BROWS;    // 1172

    size_t xbytes = (size_t)N_ * D * sizeof(__half);      // 19.2 MB
    size_t recbytes = (size_t)NB * BCAP * sizeof(uint2);  // 56.4 MB
    size_t rreg = 2 * xbytes > recbytes ? 2 * xbytes : recbytes;

    char* p = (char*)d_ws;
    __half* yA = (__half*)p;            p += xbytes;
    char* R = p;                        p += rreg;
    __half* yB   = (__half*)R;                           // aliases records
    __half* ysum = (__half*)(R + xbytes);                // (records dead by then)
    uint2* records = (uint2*)R;
    unsigned* ents = (unsigned*)p;      p += (size_t)2 * E_ * sizeof(unsigned);
    int*   rowptr = (int*)p;            p += (size_t)(N_ + 1) * 4;
    float* dinv   = (float*)p;          p += (size_t)N_ * 4;
    int*   gCursor    = (int*)p;        p += (size_t)NB * 4;
    int*   bucketBase = (int*)p;        p += (size_t)NB * 4;

    hipMemsetAsync(gCursor, 0, (size_t)NB * 4, stream);

    // L0 embeddings -> yA (holds x0 until k_build scales it to y0)
    k_user_norm<<<(U_ + 3) / 4, 256, 0, stream>>>(user_w, yA, U_);
    k_item<<<(I_ + 63) / 64, 256, 0, stream>>>(audio, artist_w, album_w, proj_W,
                                               proj_b, artist_ids, album_ids,
                                               yA, I_, U_);

    // adjacency build: fat-record scatter -> scan -> counting sort (+ y scale)
    k_scatter1<<<(E_ + PASS1_CHUNK - 1) / PASS1_CHUNK, 256, 0, stream>>>(
        u_idx, i_idx, ew, records, gCursor, E_, U_, NB);
    k_bscan<<<1, 1024, 0, stream>>>(gCursor, bucketBase, NB);
    k_build<<<NB, 256, 0, stream>>>(records, gCursor, bucketBase,
                                    ents, rowptr, dinv, (uint4*)yA, N_, NB);

    // 3 layers in y-domain; out = l2norm(y0+y1+y2+y3)
    const int ggrid = (N_ + 3) / 4;
    k_gather<<<ggrid, 256, 0, stream>>>((uint4*)yA, (uint4*)yB, (uint4*)ysum,
                                        (float4*)d_out, dinv, rowptr, ents, N_, 0);
    k_gather<<<ggrid, 256, 0, stream>>>((uint4*)yB, (uint4*)yA, (uint4*)ysum,
                                        (float4*)d_out, dinv, rowptr, ents, N_, 1);
    k_gather<<<ggrid, 256, 0, stream>>>((uint4*)yA, (uint4*)yB, (uint4*)ysum,
                                        (float4*)d_out, dinv, rowptr, ents, N_, 2);
}

// Round 2
// 462.496 us; speedup vs baseline: 1.0714x; 1.0607x over previous
//
#include <hip/hip_runtime.h>
#include <hip/hip_fp16.h>
#include <math.h>

constexpr int D = 64;
constexpr int BROWS = 128;          // dst rows per bucket (bucket = dst >> 7)
constexpr int BCAP  = 6016;         // record capacity per bucket
constexpr int PASS1_CHUNK = 4096;   // edges per workgroup in pass 1
constexpr int NBMAX = 2048;
constexpr int WROW = 136;           // fp16 LDS row stride (128 + 8 pad)

typedef _Float16 half8 __attribute__((ext_vector_type(8)));
typedef float    f32x4 __attribute__((ext_vector_type(4)));

__device__ __forceinline__ float wave_reduce_sum(float v) {
    #pragma unroll
    for (int m = 1; m < 64; m <<= 1)
        v += __shfl_xor(v, m, 64);
    return v;
}

__device__ __forceinline__ void h8_to_f8(uint4 h, float* f) {
    const __half2* hp = reinterpret_cast<const __half2*>(&h);
    #pragma unroll
    for (int i = 0; i < 4; ++i) {
        float2 t = __half22float2(hp[i]);
        f[2 * i] = t.x; f[2 * i + 1] = t.y;
    }
}

__device__ __forceinline__ uint4 f8_to_h8(const float* f) {
    uint4 r;
    unsigned* rp = &r.x;
    #pragma unroll
    for (int i = 0; i < 4; ++i) {
        __half2 h = __floats2half2_rn(f[2 * i], f[2 * i + 1]);
        rp[i] = *reinterpret_cast<unsigned*>(&h);
    }
    return r;
}

// ---- L0: user embeddings = l2norm(user_w) -> x0 fp16, wave per row ----
__global__ void k_user_norm(const float* __restrict__ user_w,
                            __half* __restrict__ x, int U_) {
    int wid  = (blockIdx.x * blockDim.x + threadIdx.x) >> 6;
    int lane = threadIdx.x & 63;
    if (wid >= U_) return;
    size_t o = (size_t)wid * D + lane;
    float v  = user_w[o];
    float ss = wave_reduce_sum(v * v);
    x[o] = __float2half(v / fmaxf(sqrtf(ss), 1e-12f));
}

// ---- L0 item projection as MFMA GEMM: [64 items/block] x [128 k] x [64 d].
__global__ void __launch_bounds__(256) k_item(
        const float* __restrict__ audio,
        const float* __restrict__ artist_w, const float* __restrict__ album_w,
        const float* __restrict__ proj_W,   const float* __restrict__ proj_b,
        const int* __restrict__ artist_ids, const int* __restrict__ album_ids,
        __half* __restrict__ x, int I_, int U_) {
    __shared__ __align__(16) __half Wh[64 * WROW];      // proj_W in fp16
    __shared__ __align__(16) __half feat[4 * 16 * WROW]; // per-wave 16x128

    const int tid  = threadIdx.x;
    const int lane = tid & 63;
    const int wv   = tid >> 6;
    const int n    = lane & 15;       // d within tile / m within tile
    const int quad = lane >> 4;

    for (int idx = tid; idx < 64 * 128; idx += 256) {
        int d = idx >> 7, k = idx & 127;
        Wh[d * WROW + k] = __float2half(proj_W[idx]);
    }
    __syncthreads();

    half8 bfrag[4][4];
    #pragma unroll
    for (int dg = 0; dg < 4; ++dg)
        #pragma unroll
        for (int c = 0; c < 4; ++c)
            bfrag[dg][c] = *reinterpret_cast<const half8*>(
                &Wh[(dg * 16 + n) * WROW + c * 32 + quad * 8]);

    __half* fw = &feat[wv * 16 * WROW];
    const int itemBase = blockIdx.x * 64 + wv * 16;
    #pragma unroll 4
    for (int it = 0; it < 16; ++it) {
        int item = itemBase + it;
        float a = 0.f, m = 0.f;
        if (item < I_) {
            a = audio[(size_t)item * D + lane];
            int aid = artist_ids[item], bid = album_ids[item];
            m = artist_w[(size_t)aid * D + lane] +
                album_w[(size_t)bid * D + lane];
        }
        fw[it * WROW + lane]      = __float2half(a);
        fw[it * WROW + 64 + lane] = __float2half(m);
    }
    __syncthreads();

    half8 afrag[4];
    #pragma unroll
    for (int c = 0; c < 4; ++c)
        afrag[c] = *reinterpret_cast<const half8*>(
            &fw[n * WROW + c * 32 + quad * 8]);

    f32x4 acc[4];
    #pragma unroll
    for (int dg = 0; dg < 4; ++dg) {
        f32x4 t = {0.f, 0.f, 0.f, 0.f};
        #pragma unroll
        for (int c = 0; c < 4; ++c)
            t = __builtin_amdgcn_mfma_f32_16x16x32_f16(afrag[c], bfrag[dg][c],
                                                       t, 0, 0, 0);
        acc[dg] = t;
    }

    float bias[4];
    #pragma unroll
    for (int dg = 0; dg < 4; ++dg) bias[dg] = proj_b[dg * 16 + n];

    float val[4][4], ss[4];
    #pragma unroll
    for (int r = 0; r < 4; ++r) {
        float s = 0.f;
        #pragma unroll
        for (int dg = 0; dg < 4; ++dg) {
            float v = acc[dg][r] + bias[dg];
            val[dg][r] = v;
            s = fmaf(v, v, s);
        }
        s += __shfl_xor(s, 1, 64);
        s += __shfl_xor(s, 2, 64);
        s += __shfl_xor(s, 4, 64);
        s += __shfl_xor(s, 8, 64);
        ss[r] = s;
    }

    #pragma unroll
    for (int r = 0; r < 4; ++r) {
        int item = itemBase + quad * 4 + r;
        if (item >= I_) continue;
        float inv = 1.0f / fmaxf(sqrtf(ss[r]), 1e-12f);
        size_t rowo = (size_t)(U_ + item) * D + n;
        #pragma unroll
        for (int dg = 0; dg < 4; ++dg)
            x[rowo + dg * 16] = __float2half(val[dg][r] * inv);
    }
}

// ---- pass 1: scatter FAT records (dst_local|src, weight) into buckets ----
__global__ void __launch_bounds__(256) k_scatter1(
        const int* __restrict__ u_idx, const int* __restrict__ i_idx,
        const float* __restrict__ ew,
        uint2* __restrict__ records, int* __restrict__ gCursor,
        int E_, int U_, int NB) {
    __shared__ int hist[NBMAX];
    __shared__ int base[NBMAX];
    const int tid = threadIdx.x;
    const int e0 = blockIdx.x * PASS1_CHUNK;
    int uu[16], vv[16]; unsigned wb[16];
    for (int b = tid; b < NB; b += 256) hist[b] = 0;
    __syncthreads();
    #pragma unroll
    for (int j = 0; j < 16; ++j) {
        int e = e0 + j * 256 + tid;
        uu[j] = -1;
        if (e < E_) {
            int u = u_idx[e];
            int v = U_ + i_idx[e];
            float w = fmaxf(ew[e], 1e-6f);
            uu[j] = u; vv[j] = v; wb[j] = __float_as_uint(w);
            atomicAdd(&hist[u >> 7], 1);
            atomicAdd(&hist[v >> 7], 1);
        }
    }
    __syncthreads();
    for (int b = tid; b < NB; b += 256) {
        int c = hist[b];
        base[b] = c ? atomicAdd(&gCursor[b], c) : 0;
        hist[b] = 0;                      // reuse as local cursor
    }
    __syncthreads();
    #pragma unroll
    for (int j = 0; j < 16; ++j) {
        if (uu[j] >= 0) {
            int u = uu[j], v = vv[j];
            int bu = u >> 7, bv = v >> 7;
            int offu = base[bu] + atomicAdd(&hist[bu], 1);
            if (offu < BCAP)   // dst=u, src=v(item node)
                records[(size_t)bu * BCAP + offu] =
                    make_uint2(((unsigned)(u & 127) << 18) | (unsigned)v, wb[j]);
            int offv = base[bv] + atomicAdd(&hist[bv], 1);
            if (offv < BCAP)   // dst=v, src=u
                records[(size_t)bv * BCAP + offv] =
                    make_uint2(((unsigned)(v & 127) << 18) | (unsigned)u, wb[j]);
        }
    }
}

// ---- exclusive scan over bucket counts (single block) ----
__global__ void __launch_bounds__(1024) k_bscan(const int* __restrict__ gCursor,
                                                int* __restrict__ bucketBase,
                                                int NB) {
    __shared__ int s[1024];
    int t = threadIdx.x;
    int e0 = (2 * t     < NB) ? min(gCursor[2 * t], BCAP)     : 0;
    int e1 = (2 * t + 1 < NB) ? min(gCursor[2 * t + 1], BCAP) : 0;
    int x = e0 + e1;
    s[t] = x; __syncthreads();
    for (int off = 1; off < 1024; off <<= 1) {
        int v = (t >= off) ? s[t - off] : 0;
        __syncthreads();
        s[t] += v;
        __syncthreads();
    }
    int excl = s[t] - x;
    if (2 * t     < NB) bucketBase[2 * t]     = excl;
    if (2 * t + 1 < NB) bucketBase[2 * t + 1] = excl + e0;
}

// ---- pass 2: per bucket, LDS counting-sort of fat records -> packed 4B ents
//      (wfix14<<18 | src18) + rowptr + dinv, plus fused yA scale. ----
__global__ void __launch_bounds__(256) k_build(
        const uint2* __restrict__ records, const int* __restrict__ gCursor,
        const int* __restrict__ bucketBase,
        unsigned* __restrict__ ents, int* __restrict__ rowptr,
        float* __restrict__ dinv, uint4* __restrict__ yAv,
        int N_, int NB) {
    __shared__ int   s_cnt[BROWS];
    __shared__ int   s_cur[BROWS];
    __shared__ float s_w[BROWS];
    const int b   = blockIdx.x;
    const int tid = threadIdx.x;
    const uint2* rec = records + (size_t)b * BCAP;
    const int R     = min(gCursor[b], BCAP);
    const int gbase = bucketBase[b];
    if (tid < BROWS) { s_cnt[tid] = 0; s_w[tid] = 0.0f; }
    __syncthreads();
    // A: per-row counts
    for (int r = tid; r < R; r += 256)
        atomicAdd(&s_cnt[(rec[r].x >> 18) & 127], 1);
    __syncthreads();
    // B: exclusive scan over 128 rows -> rowptr, cursors
    int own = (tid < BROWS) ? s_cnt[tid] : 0;
    for (int off = 1; off < BROWS; off <<= 1) {
        int v = (tid >= off && tid < BROWS) ? s_cnt[tid - off] : 0;
        __syncthreads();
        if (tid < BROWS) s_cnt[tid] += v;
        __syncthreads();
    }
    if (tid < BROWS) {
        int excl = s_cnt[tid] - own;
        s_cur[tid] = excl;
        int gid = b * BROWS + tid;
        if (gid < N_) rowptr[gid] = gbase + excl;
    }
    if (b == NB - 1 && tid == 0) rowptr[N_] = gbase + R;
    __syncthreads();
    // C: place packed entries — record already holds (src, w); no gathers
    for (int r0 = 0; r0 < R; r0 += 256 * 8) {
        uint2 rc[8];
        #pragma unroll
        for (int j = 0; j < 8; ++j) {
            int r = r0 + j * 256 + tid;
            rc[j] = (r < R) ? rec[r] : make_uint2(0xFFFFFFFFu, 0);
        }
        #pragma unroll
        for (int j = 0; j < 8; ++j) {
            if (rc[j].x != 0xFFFFFFFFu) {
                int dl  = (int)((rc[j].x >> 18) & 127);
                unsigned src = rc[j].x & 0x3FFFFu;
                float w = __uint_as_float(rc[j].y);
                unsigned wfix = (unsigned)fminf(w * 16384.f + 0.5f, 16383.f);
                int pos = gbase + atomicAdd(&s_cur[dl], 1);
                ents[pos] = (wfix << 18) | src;
                atomicAdd(&s_w[dl], w);
            }
        }
    }
    __syncthreads();
    // D: dinv = rsqrt(wsum + 1)
    if (tid < BROWS) {
        int gid = b * BROWS + tid;
        if (gid < N_) {
            float di = 1.0f / sqrtf(s_w[tid] + 1.0f);
            dinv[gid] = di;
            s_w[tid] = di;
        }
    }
    __syncthreads();
    // E: scale this bucket's yA rows: y0 = dinv * x0  (16 B per lane)
    for (int t = tid; t < BROWS * 8; t += 256) {
        int r = t >> 3, c8 = t & 7;
        int gid = b * BROWS + r;
        if (gid < N_) {
            float di = s_w[r];
            size_t o = (size_t)gid * 8 + c8;
            float f[8]; h8_to_f8(yAv[o], f);
            #pragma unroll
            for (int i = 0; i < 8; ++i) f[i] *= di;
            yAv[o] = f8_to_h8(f);
        }
    }
}

// ---- propagation layer in y-domain: s = y[dst] + 2^-14 * sum wfix*y[src];
//      y_next = dinv^2 * s.  8-lane row groups, half8 (16 B) per lane.
//      MLP-deep version: group g owns the CONTIGUOUS ent range
//      [beg+g*L, beg+(g+1)*L), L=ceil(deg/8), processed in predicated
//      batches of 4: 4 independent ent loads -> 4 independent row loads
//      all in flight (up to 32 rows / 4 KB outstanding per wave) before
//      any consumption.  Epilogue operands (yold/ysum/dinv) are issued
//      BEFORE the loop so their latency hides under the gather.
// mode 0: write yn = y1; ysum = y0 + y1
// mode 1: write yn = y2; ysum += y2
// mode 2: out = l2norm(ysum + y3)        (yn unused)
__global__ void __launch_bounds__(256) k_gather(
        const uint4* __restrict__ ys, uint4* __restrict__ yn,
        uint4* __restrict__ ysum, float4* __restrict__ outp,
        const float* __restrict__ dinv, const int* __restrict__ rowptr,
        const unsigned* __restrict__ ents, int N_, int mode) {
    const int lane = threadIdx.x & 63;
    const int g  = lane >> 3;            // edge group 0..7
    const int c8 = lane & 7;             // half8 index within row
    const int wid = __builtin_amdgcn_readfirstlane(
                        (int)((blockIdx.x * blockDim.x + threadIdx.x) >> 6));
    if (wid >= N_) return;
    const int beg = rowptr[wid], end = rowptr[wid + 1];
    const size_t ro = (size_t)wid * 8 + c8;

    // hoisted epilogue operands — issue early, consume after the loop
    const float di = dinv[wid];
    uint4 hold, hsum;
    if (mode == 2 || g < 2)                  hold = ys[ro];
    if (mode == 2 || (mode == 1 && g == 1))  hsum = ysum[ro];

    const int deg = end - beg;
    const int L   = (deg + 7) >> 3;          // per-group contiguous span
    int j         = beg + g * L;
    const int je  = min(j + L, end);

    float a[8] = {0.f, 0.f, 0.f, 0.f, 0.f, 0.f, 0.f, 0.f};
    while (j < je) {
        int m = je - j; if (m > 4) m = 4;
        unsigned e[4];
        uint4 h[4];
        e[0] = ents[j];
        if (m > 1) e[1] = ents[j + 1];
        if (m > 2) e[2] = ents[j + 2];
        if (m > 3) e[3] = ents[j + 3];
        h[0] = ys[(size_t)(e[0] & 0x3FFFFu) * 8 + c8];
        if (m > 1) h[1] = ys[(size_t)(e[1] & 0x3FFFFu) * 8 + c8];
        if (m > 2) h[2] = ys[(size_t)(e[2] & 0x3FFFFu) * 8 + c8];
        if (m > 3) h[3] = ys[(size_t)(e[3] & 0x3FFFFu) * 8 + c8];
        #pragma unroll
        for (int t = 0; t < 4; ++t) {
            if (t < m) {
                float wf = (float)(e[t] >> 18);
                const __half2* hp = reinterpret_cast<const __half2*>(&h[t]);
                #pragma unroll
                for (int i = 0; i < 4; ++i) {
                    float2 f2 = __half22float2(hp[i]);
                    a[2 * i]     = fmaf(wf, f2.x, a[2 * i]);
                    a[2 * i + 1] = fmaf(wf, f2.y, a[2 * i + 1]);
                }
            }
        }
        j += 4;
    }

    // reduce the 8 group partials (lanes sharing c8)
    #pragma unroll
    for (int i = 0; i < 8; ++i) {
        a[i] += __shfl_xor(a[i], 8, 64);
        a[i] += __shfl_xor(a[i], 16, 64);
        a[i] += __shfl_xor(a[i], 32, 64);
    }

    float yold[8]; h8_to_f8(hold, yold);
    float d2 = di * di;
    float fin[8];
    #pragma unroll
    for (int i = 0; i < 8; ++i)
        fin[i] = d2 * fmaf(a[i], 1.0f / 16384.0f, yold[i]);

    if (mode == 2) {
        float vs[8]; h8_to_f8(hsum, vs);
        float vv[8], sq = 0.f;
        #pragma unroll
        for (int i = 0; i < 8; ++i) {
            vv[i] = vs[i] + fin[i];
            sq = fmaf(vv[i], vv[i], sq);
        }
        sq += __shfl_xor(sq, 1, 64);
        sq += __shfl_xor(sq, 2, 64);
        sq += __shfl_xor(sq, 4, 64);
        float inv = 1.0f / fmaxf(sqrtf(sq), 1e-12f);
        if (g == 0) {
            size_t ob = (size_t)wid * 16 + c8 * 2;
            outp[ob]     = make_float4(vv[0] * inv, vv[1] * inv,
                                       vv[2] * inv, vv[3] * inv);
            outp[ob + 1] = make_float4(vv[4] * inv, vv[5] * inv,
                                       vv[6] * inv, vv[7] * inv);
        }
    } else {
        if (g == 0) yn[ro] = f8_to_h8(fin);
        if (g == 1) {
            float t[8];
            if (mode == 0) {
                #pragma unroll
                for (int i = 0; i < 8; ++i) t[i] = yold[i] + fin[i];
            } else {
                float vs[8]; h8_to_f8(hsum, vs);
                #pragma unroll
                for (int i = 0; i < 8; ++i) t[i] = vs[i] + fin[i];
            }
            ysum[ro] = f8_to_h8(t);
        }
    }
}

extern "C" void kernel_launch(void* const* d_in, const int* in_sizes, int n_in,
                              void* d_out, int out_size, void* d_ws, size_t ws_size,
                              hipStream_t stream) {
    const float* user_w     = (const float*)d_in[0];
    const float* audio      = (const float*)d_in[1];
    const float* artist_w   = (const float*)d_in[2];
    const float* album_w    = (const float*)d_in[3];
    const float* proj_W     = (const float*)d_in[4];
    const float* proj_b     = (const float*)d_in[5];
    const float* ew         = (const float*)d_in[6];
    const int*   u_idx      = (const int*)d_in[7];
    const int*   i_idx      = (const int*)d_in[8];
    const int*   artist_ids = (const int*)d_in[9];
    const int*   album_ids  = (const int*)d_in[10];

    const int U_ = in_sizes[0] / D;
    const int I_ = in_sizes[1] / D;
    const int E_ = in_sizes[6];
    const int N_ = U_ + I_;
    const int NB = (N_ + BROWS - 1) / BROWS;    // 1172

    size_t xbytes = (size_t)N_ * D * sizeof(__half);      // 19.2 MB
    size_t recbytes = (size_t)NB * BCAP * sizeof(uint2);  // 56.4 MB
    size_t rreg = 2 * xbytes > recbytes ? 2 * xbytes : recbytes;

    char* p = (char*)d_ws;
    __half* yA = (__half*)p;            p += xbytes;
    char* R = p;                        p += rreg;
    __half* yB   = (__half*)R;                           // aliases records
    __half* ysum = (__half*)(R + xbytes);                // (records dead by then)
    uint2* records = (uint2*)R;
    unsigned* ents = (unsigned*)p;      p += (size_t)2 * E_ * sizeof(unsigned);
    int*   rowptr = (int*)p;            p += (size_t)(N_ + 1) * 4;
    float* dinv   = (float*)p;          p += (size_t)N_ * 4;
    int*   gCursor    = (int*)p;        p += (size_t)NB * 4;
    int*   bucketBase = (int*)p;        p += (size_t)NB * 4;

    hipMemsetAsync(gCursor, 0, (size_t)NB * 4, stream);

    // L0 embeddings -> yA (holds x0 until k_build scales it to y0)
    k_user_norm<<<(U_ + 3) / 4, 256, 0, stream>>>(user_w, yA, U_);
    k_item<<<(I_ + 63) / 64, 256, 0, stream>>>(audio, artist_w, album_w, proj_W,
                                               proj_b, artist_ids, album_ids,
                                               yA, I_, U_);

    // adjacency build: fat-record scatter -> scan -> counting sort (+ y scale)
    k_scatter1<<<(E_ + PASS1_CHUNK - 1) / PASS1_CHUNK, 256, 0, stream>>>(
        u_idx, i_idx, ew, records, gCursor, E_, U_, NB);
    k_bscan<<<1, 1024, 0, stream>>>(gCursor, bucketBase, NB);
    k_build<<<NB, 256, 0, stream>>>(records, gCursor, bucketBase,
                                    ents, rowptr, dinv, (uint4*)yA, N_, NB);

    // 3 layers in y-domain; out = l2norm(y0+y1+y2+y3)
    const int ggrid = (N_ + 3) / 4;
    k_gather<<<ggrid, 256, 0, stream>>>((uint4*)yA, (uint4*)yB, (uint4*)ysum,
                                        (float4*)d_out, dinv, rowptr, ents, N_, 0);
    k_gather<<<ggrid, 256, 0, stream>>>((uint4*)yB, (uint4*)yA, (uint4*)ysum,
                                        (float4*)d_out, dinv, rowptr, ents, N_, 1);
    k_gather<<<ggrid, 256, 0, stream>>>((uint4*)yA, (uint4*)yB, (uint4*)ysum,
                                        (float4*)d_out, dinv, rowptr, ents, N_, 2);
}